// Round 3
// baseline (1634.877 us; speedup 1.0000x reference)
//
#include <hip/hip_runtime.h>
#include <math.h>

#define HH 192
#define WW 448
#define HW (HH * WW)      // 86016
#define PW2 450           // padded width
#define PH2 194           // padded height
#define NPAD 87300        // 194*450 valid padded pixels
#define NPADT 87552       // padded to 684*128 tiles
#define GUARD 1024        // guard pixels before/after each buffer
#define NB 4

typedef _Float16 half8 __attribute__((ext_vector_type(8)));
typedef _Float16 half4v __attribute__((ext_vector_type(4)));
typedef float float4v __attribute__((ext_vector_type(4)));

// ---------------------------------------------------------------------------
// per-(b,c) mean of flow over H*W  -> means[8]
// ---------------------------------------------------------------------------
__global__ void mean_kernel(const float* __restrict__ flow, float* __restrict__ means) {
    int bc = blockIdx.x;
    const float* src = flow + (size_t)bc * HW;
    float s = 0.f;
    for (int i = threadIdx.x; i < HW; i += 256) s += src[i];
    __shared__ float red[256];
    red[threadIdx.x] = s;
    __syncthreads();
    for (int off = 128; off > 0; off >>= 1) {
        if (threadIdx.x < off) red[threadIdx.x] += red[threadIdx.x + off];
        __syncthreads();
    }
    if (threadIdx.x == 0) means[bc] = red[0] * (1.0f / (float)HW);
}

// ---------------------------------------------------------------------------
// weight transform: OIHW fp32 -> [shift][chunk][oc][k=32] fp16, zero-padded K
// perm=1: conv1 channel permutation (buffer: 0..127=feat->ref ic 3..130,
//         128..130 = diff,fx,fy -> ref ic 0..2, 131..159 -> zero)
// ---------------------------------------------------------------------------
__global__ void wtrans_kernel(const float* __restrict__ w, _Float16* __restrict__ wt,
                              int cinReal, int nchunk, int cout, int nshift, int perm,
                              int total) {
    int idx = blockIdx.x * 256 + threadIdx.x;
    if (idx >= total) return;
    int k = idx & 31;
    int r = idx >> 5;
    int m = r % cout;
    int r2 = r / cout;
    int q = r2 % nchunk;
    int s = r2 / nchunk;
    int icb = q * 32 + k;
    float val = 0.f;
    if (perm) {
        if (icb < 131) {
            int icr = (icb < 128) ? icb + 3 : icb - 128;
            val = w[((size_t)m * cinReal + icr) * nshift + s];
        }
    } else if (icb < cinReal) {
        val = w[((size_t)m * cinReal + icb) * nshift + s];
    }
    wt[idx] = (_Float16)val;
}

// ---------------------------------------------------------------------------
// features NCHW fp32 -> padded NHWC fp16 (64 ch), LDS-tiled transpose
// ---------------------------------------------------------------------------
__global__ void feat_transpose(const float* __restrict__ feat, _Float16* __restrict__ F,
                               size_t fSlot) {
    __shared__ _Float16 tile[64 * 72];
    int t = threadIdx.x;
    int z = blockIdx.y;
    int pix0 = blockIdx.x * 64;  // 64 | 448 -> never crosses a row
    const float* src = feat + (size_t)z * 64 * HW + pix0;
#pragma unroll
    for (int pass = 0; pass < 16; ++pass) {
        int c = pass * 4 + (t >> 6);
        int pl = t & 63;
        tile[pl * 72 + c] = (_Float16)src[(size_t)c * HW + pl];
    }
    __syncthreads();
    int row = pix0 / WW;
    int xcol = pix0 - row * WW;
    size_t n0 = (size_t)(row + 1) * PW2 + xcol + 1;
    _Float16* dst = F + (size_t)z * fSlot + n0 * 64;
#pragma unroll
    for (int pass = 0; pass < 2; ++pass) {
        int pl = (t >> 3) + pass * 32;
        int seg = t & 7;
        *(half8*)&dst[(size_t)pl * 64 + seg * 8] = *(const half8*)&tile[pl * 72 + seg * 8];
    }
}

// ---------------------------------------------------------------------------
// prep: diff + centered flow -> bufA channels 128..130 (NHWC fp16, stride 160)
// ---------------------------------------------------------------------------
__global__ void prep_kernel(const float* __restrict__ t1, const float* __restrict__ t2,
                            const float* __restrict__ flow, const float* __restrict__ means,
                            _Float16* __restrict__ bufA, size_t aSlot) {
    int n = blockIdx.x * 256 + threadIdx.x;
    if (n >= NPAD) return;
    int z = blockIdx.y;
    _Float16* dst = bufA + (size_t)z * aSlot + (size_t)n * 160 + 128;
    int y = n / PW2, x = n - PW2 * y;
    if (y < 1 || y > HH || x < 1 || x > WW) {
        dst[0] = (_Float16)0.f; dst[1] = (_Float16)0.f; dst[2] = (_Float16)0.f;
        return;
    }
    int iy = y - 1, ix = x - 1, pix = iy * WW + ix;
    const float* fb = flow + (size_t)z * 2 * HW;
    float fx = fb[pix];
    float fy = fb[HW + pix];
    float sx = (float)ix + fx * 5.0f;
    float sy = (float)iy + fy * 5.0f;
    float fx0 = floorf(sx), fy0 = floorf(sy);
    float wx1 = sx - fx0, wy1 = sy - fy0;
    float wx0 = 1.f - wx1, wy0 = 1.f - wy1;
    int ix0 = (int)fx0, iy0 = (int)fy0;
    bool y0ok = (iy0 >= 0) && (iy0 < HH);
    bool y1ok = (iy0 + 1 >= 0) && (iy0 + 1 < HH);
    bool x0ok = (ix0 >= 0) && (ix0 < WW);
    bool x1ok = (ix0 + 1 >= 0) && (ix0 + 1 < WW);
    float d2 = 0.f;
    for (int c = 0; c < 3; ++c) {
        const float* img = t2 + ((size_t)z * 3 + c) * HW;
        float v00 = (y0ok && x0ok) ? img[iy0 * WW + ix0] : 0.f;
        float v01 = (y0ok && x1ok) ? img[iy0 * WW + ix0 + 1] : 0.f;
        float v10 = (y1ok && x0ok) ? img[(iy0 + 1) * WW + ix0] : 0.f;
        float v11 = (y1ok && x1ok) ? img[(iy0 + 1) * WW + ix0 + 1] : 0.f;
        float v = v00 * (wy0 * wx0) + v01 * (wy0 * wx1) + v10 * (wy1 * wx0) + v11 * (wy1 * wx1);
        float d = t1[((size_t)z * 3 + c) * HW + pix] - v;
        d2 += d * d;
    }
    dst[0] = (_Float16)sqrtf(d2);
    dst[1] = (_Float16)(fx - means[z * 2 + 0]);
    dst[2] = (_Float16)(fy - means[z * 2 + 1]);
}

// ---------------------------------------------------------------------------
// fp16 MFMA implicit-GEMM conv — NO LDS, no barriers.
// Both fragments loaded straight from global (NHWC activations, pre-swizzled
// weights); register double-buffer; compiler interleaves loads with MFMAs.
// BM = Cout (2x2 wave grid), BN = 128 pixels, K = NCHUNK*32 x KH*KW shifts.
// ---------------------------------------------------------------------------
template <int BM, int KH, int KW, int CSIN, int NCHUNK, int CSOUT>
__launch_bounds__(256, (BM > 64) ? 3 : 4)
__global__ void mfma_conv(const _Float16* __restrict__ in, size_t inSlot,
                          const _Float16* __restrict__ wt,
                          const float* __restrict__ bias,
                          _Float16* __restrict__ out, size_t outSlot) {
    constexpr int MT = BM / 32;       // MFMA m-tiles per wave
    constexpr int NIT = KH * KW * NCHUNK;
    const int t = threadIdx.x;
    const int wave = t >> 6, lane = t & 63;
    const int wm = wave >> 1, wn = wave & 1;
    const int col = lane & 15, quad = lane >> 4;
    const int n0 = blockIdx.x * 128;
    const _Float16* inImg = in + (size_t)blockIdx.z * inSlot;
    _Float16* outImg = out + (size_t)blockIdx.z * outSlot;

    // per-lane fragment base pointers
    const _Float16* aBase = wt + ((size_t)(wm * MT * 16 + col)) * 32 + quad * 8;
    const _Float16* bBase = inImg + ((ptrdiff_t)(n0 + wn * 64 + col)) * CSIN + quad * 8;

    float4v acc[MT][4];
#pragma unroll
    for (int i = 0; i < MT; ++i)
#pragma unroll
        for (int j = 0; j < 4; ++j) acc[i][j] = float4v{0.f, 0.f, 0.f, 0.f};

    half8 aF[2][MT], bF[2][4];
    auto ld = [&](int it, int buf) {
        const int s = it / NCHUNK, q = it - s * NCHUNK;
        const int off = (s / KW - KH / 2) * PW2 + (s % KW - KW / 2);
        const _Float16* ap = aBase + (size_t)it * (BM * 32);
#pragma unroll
        for (int mt = 0; mt < MT; ++mt)
            aF[buf][mt] = *(const half8*)(ap + mt * 16 * 32);
        const _Float16* bp = bBase + (ptrdiff_t)off * CSIN + q * 32;
#pragma unroll
        for (int nt = 0; nt < 4; ++nt)
            bF[buf][nt] = *(const half8*)(bp + (ptrdiff_t)nt * 16 * CSIN);
    };

    ld(0, 0);
#pragma unroll
    for (int it = 0; it < NIT; ++it) {
        const int cur = it & 1;
        if (it + 1 < NIT) ld(it + 1, cur ^ 1);
#pragma unroll
        for (int mt = 0; mt < MT; ++mt)
#pragma unroll
            for (int nt = 0; nt < 4; ++nt)
                acc[mt][nt] = __builtin_amdgcn_mfma_f32_16x16x32_f16(
                    aF[cur][mt], bF[cur][nt], acc[mt][nt], 0, 0, 0);
    }

    // epilogue: bias + lrelu + border mask, NHWC fp16 8B stores
#pragma unroll
    for (int mt = 0; mt < MT; ++mt) {
        const int m0 = wm * MT * 16 + mt * 16 + quad * 4;
        float bv[4];
#pragma unroll
        for (int i = 0; i < 4; ++i) bv[i] = bias[m0 + i];
#pragma unroll
        for (int nt = 0; nt < 4; ++nt) {
            int n = n0 + wn * 64 + nt * 16 + col;
            int y = n / PW2, x = n - y * PW2;
            bool ok = (y >= 1) && (y <= HH) && (x >= 1) && (x <= WW) && (n < NPAD);
            half4v h;
#pragma unroll
            for (int i = 0; i < 4; ++i) {
                float v = acc[mt][nt][i] + bv[i];
                v = (v >= 0.f) ? v : 0.1f * v;
                h[i] = ok ? (_Float16)v : (_Float16)0.f;
            }
            *(half4v*)&outImg[(size_t)n * CSOUT + m0] = h;
        }
    }
}

// ---------------------------------------------------------------------------
// dist1: 5x1 conv (pad 2,0), 32ch fp16 NHWC-padded in -> 25ch fp32 NHWC out
// ---------------------------------------------------------------------------
__global__ void dist1_kernel(const _Float16* __restrict__ in, size_t inSlot,
                             const float* __restrict__ w, const float* __restrict__ bias,
                             float* __restrict__ outD, size_t outSlot) {
    __shared__ float wl[25 * 32 * 5];
    int t = threadIdx.x;
    for (int i = t; i < 4000; i += 256) wl[i] = w[i];
    __syncthreads();
    int p = blockIdx.x * 256 + t;
    int z = blockIdx.y;
    const _Float16* inI = in + (size_t)z * inSlot;
    float* out = outD + (size_t)z * outSlot;
    int y = p / WW, x = p - y * WW;
    float acc[25];
#pragma unroll
    for (int oc = 0; oc < 25; ++oc) acc[oc] = bias[oc];
    for (int kh = 0; kh < 5; ++kh) {
        int yy = y + kh - 2;
        if (yy < 0 || yy >= HH) continue;
        const _Float16* src = inI + (size_t)((yy + 1) * PW2 + x + 1) * 32;
        _Float16 vals[32];
#pragma unroll
        for (int g = 0; g < 4; ++g) *(half8*)&vals[g * 8] = *(const half8*)&src[g * 8];
#pragma unroll
        for (int ic = 0; ic < 32; ++ic) {
            float v = (float)vals[ic];
#pragma unroll
            for (int oc = 0; oc < 25; ++oc)
                acc[oc] = fmaf(v, wl[(oc * 32 + ic) * 5 + kh], acc[oc]);
        }
    }
#pragma unroll
    for (int oc = 0; oc < 25; ++oc) out[(size_t)p * 25 + oc] = acc[oc];
}

// ---------------------------------------------------------------------------
// final fused: dist2 (1x5) + softmax(-(d^2)) + unfold-weighted flow average
// ---------------------------------------------------------------------------
__global__ void final_kernel(const float* __restrict__ D1, size_t d1Slot,
                             const float* __restrict__ flow,
                             const float* __restrict__ dw2, const float* __restrict__ db2,
                             const float* __restrict__ sxw, const float* __restrict__ sxb,
                             const float* __restrict__ syw, const float* __restrict__ syb,
                             float* __restrict__ out) {
    __shared__ float wl[25 * 25 * 5];
    int t = threadIdx.x;
    for (int i = t; i < 3125; i += 256) wl[i] = dw2[i];
    __syncthreads();
    int p = blockIdx.x * 256 + t;
    int z = blockIdx.y;
    const float* D = D1 + (size_t)z * d1Slot;
    int y = p / WW, x = p - y * WW;
    float acc[25];
#pragma unroll
    for (int oc = 0; oc < 25; ++oc) acc[oc] = db2[oc];
    for (int kw = 0; kw < 5; ++kw) {
        int xx = x + kw - 2;
        if (xx < 0 || xx >= WW) continue;
        const float* src = D + (size_t)(y * WW + xx) * 25;
#pragma unroll
        for (int ic = 0; ic < 25; ++ic) {
            float v = src[ic];
#pragma unroll
            for (int oc = 0; oc < 25; ++oc)
                acc[oc] = fmaf(v, wl[(oc * 25 + ic) * 5 + kw], acc[oc]);
        }
    }
    float e[25];
    float m = -1e30f;
#pragma unroll
    for (int c = 0; c < 25; ++c) {
        float d = -(acc[c] * acc[c]);
        e[c] = d;
        m = fmaxf(m, d);
    }
    float s = 0.f;
#pragma unroll
    for (int c = 0; c < 25; ++c) {
        e[c] = expf(e[c] - m);
        s += e[c];
    }
    const float* f0 = flow + (size_t)z * 2 * HW;
    const float* f1 = f0 + HW;
    float ax = sxb[0], ay = syb[0];
#pragma unroll
    for (int kh = 0; kh < 5; ++kh) {
        int iy = y + kh - 2;
        bool yok = (iy >= 0) && (iy < HH);
#pragma unroll
        for (int kw = 0; kw < 5; ++kw) {
            int ix = x + kw - 2;
            int c = kh * 5 + kw;
            float u1 = 0.f, u2 = 0.f;
            if (yok && ix >= 0 && ix < WW) {
                int q = iy * WW + ix;
                u1 = f0[q];
                u2 = f1[q];
            }
            ax = fmaf(e[c] * u1, sxw[c], ax);
            ay = fmaf(e[c] * u2, syw[c], ay);
        }
    }
    float inv = 1.0f / s;
    out[(size_t)z * 2 * HW + p] = ax * inv;
    out[(size_t)z * 2 * HW + HW + p] = ay * inv;
}

// ---------------------------------------------------------------------------
extern "C" void kernel_launch(void* const* d_in, const int* in_sizes, int n_in,
                              void* d_out, int out_size, void* d_ws, size_t ws_size,
                              hipStream_t stream) {
    const float* t1      = (const float*)d_in[0];
    const float* t2      = (const float*)d_in[1];
    const float* feat_in = (const float*)d_in[2];
    const float* flow    = (const float*)d_in[4];
    const float* feat_w  = (const float*)d_in[5];
    const float* feat_b  = (const float*)d_in[6];
    const float* w1 = (const float*)d_in[7];   const float* b1 = (const float*)d_in[8];
    const float* w2 = (const float*)d_in[9];   const float* b2 = (const float*)d_in[10];
    const float* w3 = (const float*)d_in[11];  const float* b3 = (const float*)d_in[12];
    const float* w4 = (const float*)d_in[13];  const float* b4 = (const float*)d_in[14];
    const float* w5 = (const float*)d_in[15];  const float* b5 = (const float*)d_in[16];
    const float* w6 = (const float*)d_in[17];  const float* b6 = (const float*)d_in[18];
    const float* dw1 = (const float*)d_in[19]; const float* db1 = (const float*)d_in[20];
    const float* dw2 = (const float*)d_in[21]; const float* db2 = (const float*)d_in[22];
    const float* sxw = (const float*)d_in[23]; const float* sxb = (const float*)d_in[24];
    const float* syw = (const float*)d_in[25]; const float* syb = (const float*)d_in[26];
    float* out = (float*)d_out;
    char* ws = (char*)d_ws;

    // Wt layout offsets (fp16 elems)
    const size_t OFF_FEAT = 0;        // 1 shift x 2 chunks x 128 x 32 = 8192
    const size_t OFF_C1 = 8192;       // 9x5x128x32 = 184320
    const size_t OFF_C2 = 192512;     // 9x4x128x32 = 147456
    const size_t OFF_C3 = 339968;     // 9x4x64x32  = 73728
    const size_t OFF_C4 = 413696;     // 9x2x64x32  = 36864
    const size_t OFF_C5 = 450560;     // 9x2x32x32  = 18432
    const size_t OFF_C6 = 468992;     // 9x1x32x32  = 9216
    const size_t WT_BYTES = 478208 * 2;  // 956416

    _Float16* wt = (_Float16*)ws;
    float* means = (float*)(ws + WT_BYTES);           // 32 B
    const size_t F0 = WT_BYTES + 64;                  // 956480, 16B aligned
    const size_t F_SLOT_B = (size_t)(NPADT + 2 * GUARD) * 64 * 2;   // 11,468,800
    const size_t A_SLOT_B = (size_t)(NPADT + 2 * GUARD) * 160 * 2;  // 28,672,000
    const size_t B_SLOT_B = (size_t)(NPADT + 2 * GUARD) * 128 * 2;  // 22,937,600
    const size_t C_SLOT_B = B_SLOT_B;
    const size_t PER_IMG = F_SLOT_B + A_SLOT_B + B_SLOT_B + C_SLOT_B;  // 86,016,000
    const size_t needFull = F0 + NB * PER_IMG;
    const int step = (ws_size >= needFull) ? NB : 1;

    const size_t A0 = F0 + step * F_SLOT_B;
    const size_t B0 = A0 + step * A_SLOT_B;
    const size_t C0 = B0 + step * B_SLOT_B;

    // data bases (past guard) per channel-stride interpretation
    _Float16* Fd    = (_Float16*)(ws + F0) + (size_t)GUARD * 64;
    _Float16* Ad    = (_Float16*)(ws + A0) + (size_t)GUARD * 160;
    _Float16* Bd128 = (_Float16*)(ws + B0) + (size_t)GUARD * 128;
    _Float16* Bd64  = (_Float16*)(ws + B0) + (size_t)GUARD * 64;
    _Float16* Bd32  = (_Float16*)(ws + B0) + (size_t)GUARD * 32;
    _Float16* Cd128 = (_Float16*)(ws + C0) + (size_t)GUARD * 128;
    _Float16* Cd64  = (_Float16*)(ws + C0) + (size_t)GUARD * 64;
    _Float16* Cd32  = (_Float16*)(ws + C0) + (size_t)GUARD * 32;
    float* D1 = (float*)(ws + F0);  // reuses F region (dead after feat conv)

    const size_t FSL = F_SLOT_B / 2, ASL = A_SLOT_B / 2, BSL = B_SLOT_B / 2,
                 CSL = C_SLOT_B / 2, DSL = F_SLOT_B / 4;

    mean_kernel<<<8, 256, 0, stream>>>(flow, means);

    // weight transforms (run every call; ws is re-poisoned)
    auto wlaunch = [&](const float* src, size_t dst, int cin, int nch, int cout,
                       int nsh, int perm) {
        int total = nsh * nch * cout * 32;
        wtrans_kernel<<<(total + 255) / 256, 256, 0, stream>>>(
            src, wt + dst, cin, nch, cout, nsh, perm, total);
    };
    wlaunch(feat_w, OFF_FEAT, 64, 2, 128, 1, 0);
    wlaunch(w1, OFF_C1, 131, 5, 128, 9, 1);
    wlaunch(w2, OFF_C2, 128, 4, 128, 9, 0);
    wlaunch(w3, OFF_C3, 128, 4, 64, 9, 0);
    wlaunch(w4, OFF_C4, 64, 2, 64, 9, 0);
    wlaunch(w5, OFF_C5, 64, 2, 32, 9, 0);
    wlaunch(w6, OFF_C6, 32, 1, 32, 9, 0);

    const int NT = NPADT / 128;  // 684 N-tiles per image

    for (int b0 = 0; b0 < NB; b0 += step) {
        dim3 gconv(NT, 1, step);
        feat_transpose<<<dim3(HW / 64, step), 256, 0, stream>>>(
            feat_in + (size_t)b0 * 64 * HW, Fd, FSL);
        prep_kernel<<<dim3((NPAD + 255) / 256, step), 256, 0, stream>>>(
            t1 + (size_t)b0 * 3 * HW, t2 + (size_t)b0 * 3 * HW,
            flow + (size_t)b0 * 2 * HW, means + b0 * 2, Ad, ASL);
        mfma_conv<128, 1, 1, 64, 2, 160><<<gconv, 256, 0, stream>>>(
            Fd, FSL, wt + OFF_FEAT, feat_b, Ad, ASL);
        mfma_conv<128, 3, 3, 160, 5, 128><<<gconv, 256, 0, stream>>>(
            Ad, ASL, wt + OFF_C1, b1, Bd128, BSL);
        mfma_conv<128, 3, 3, 128, 4, 128><<<gconv, 256, 0, stream>>>(
            Bd128, BSL, wt + OFF_C2, b2, Cd128, CSL);
        mfma_conv<64, 3, 3, 128, 4, 64><<<gconv, 256, 0, stream>>>(
            Cd128, CSL, wt + OFF_C3, b3, Bd64, BSL);
        mfma_conv<64, 3, 3, 64, 2, 64><<<gconv, 256, 0, stream>>>(
            Bd64, BSL, wt + OFF_C4, b4, Cd64, CSL);
        mfma_conv<32, 3, 3, 64, 2, 32><<<gconv, 256, 0, stream>>>(
            Cd64, CSL, wt + OFF_C5, b5, Bd32, BSL);
        mfma_conv<32, 3, 3, 32, 1, 32><<<gconv, 256, 0, stream>>>(
            Bd32, BSL, wt + OFF_C6, b6, Cd32, CSL);
        dist1_kernel<<<dim3(HW / 256, step), 256, 0, stream>>>(
            Cd32, CSL, dw1, db1, D1, DSL);
        final_kernel<<<dim3(HW / 256, step), 256, 0, stream>>>(
            D1, DSL, flow + (size_t)b0 * 2 * HW, dw2, db2, sxw, sxb, syw, syb,
            out + (size_t)b0 * 2 * HW);
    }
}

// Round 4
// 1248.361 us; speedup vs baseline: 1.3096x; 1.3096x over previous
//
#include <hip/hip_runtime.h>
#include <math.h>

#define HH 192
#define WW 448
#define HW (HH * WW)      // 86016
#define PW2 450           // padded width
#define PH2 194           // padded height
#define NPAD 87300        // 194*450 valid padded pixels
#define NPADT 87552       // padded to 684*128 tiles
#define GUARD 1024        // guard pixels before/after each buffer
#define NB 4

typedef _Float16 half8 __attribute__((ext_vector_type(8)));
typedef _Float16 half4v __attribute__((ext_vector_type(4)));
typedef float float4v __attribute__((ext_vector_type(4)));

// ---------------------------------------------------------------------------
// per-(b,c) mean of flow over H*W  -> means[8]
// ---------------------------------------------------------------------------
__global__ void mean_kernel(const float* __restrict__ flow, float* __restrict__ means) {
    int bc = blockIdx.x;
    const float* src = flow + (size_t)bc * HW;
    float s = 0.f;
    for (int i = threadIdx.x; i < HW; i += 256) s += src[i];
    __shared__ float red[256];
    red[threadIdx.x] = s;
    __syncthreads();
    for (int off = 128; off > 0; off >>= 1) {
        if (threadIdx.x < off) red[threadIdx.x] += red[threadIdx.x + off];
        __syncthreads();
    }
    if (threadIdx.x == 0) means[bc] = red[0] * (1.0f / (float)HW);
}

// ---------------------------------------------------------------------------
// weight transform: OIHW fp32 -> [shift][chunk][oc][k=32] fp16, zero-padded K
// perm=1: conv1 channel permutation (buffer: 0..127=feat->ref ic 3..130,
//         128..130 = diff,fx,fy -> ref ic 0..2, 131..159 -> zero)
// ---------------------------------------------------------------------------
__global__ void wtrans_kernel(const float* __restrict__ w, _Float16* __restrict__ wt,
                              int cinReal, int nchunk, int cout, int nshift, int perm,
                              int total) {
    int idx = blockIdx.x * 256 + threadIdx.x;
    if (idx >= total) return;
    int k = idx & 31;
    int r = idx >> 5;
    int m = r % cout;
    int r2 = r / cout;
    int q = r2 % nchunk;
    int s = r2 / nchunk;
    int icb = q * 32 + k;
    float val = 0.f;
    if (perm) {
        if (icb < 131) {
            int icr = (icb < 128) ? icb + 3 : icb - 128;
            val = w[((size_t)m * cinReal + icr) * nshift + s];
        }
    } else if (icb < cinReal) {
        val = w[((size_t)m * cinReal + icb) * nshift + s];
    }
    wt[idx] = (_Float16)val;
}

// ---------------------------------------------------------------------------
// features NCHW fp32 -> padded NHWC fp16 (64 ch), LDS-tiled transpose
// ---------------------------------------------------------------------------
__global__ void feat_transpose(const float* __restrict__ feat, _Float16* __restrict__ F,
                               size_t fSlot) {
    __shared__ _Float16 tile[64 * 72];
    int t = threadIdx.x;
    int z = blockIdx.y;
    int pix0 = blockIdx.x * 64;  // 64 | 448 -> never crosses a row
    const float* src = feat + (size_t)z * 64 * HW + pix0;
#pragma unroll
    for (int pass = 0; pass < 16; ++pass) {
        int c = pass * 4 + (t >> 6);
        int pl = t & 63;
        tile[pl * 72 + c] = (_Float16)src[(size_t)c * HW + pl];
    }
    __syncthreads();
    int row = pix0 / WW;
    int xcol = pix0 - row * WW;
    size_t n0 = (size_t)(row + 1) * PW2 + xcol + 1;
    _Float16* dst = F + (size_t)z * fSlot + n0 * 64;
#pragma unroll
    for (int pass = 0; pass < 2; ++pass) {
        int pl = (t >> 3) + pass * 32;
        int seg = t & 7;
        *(half8*)&dst[(size_t)pl * 64 + seg * 8] = *(const half8*)&tile[pl * 72 + seg * 8];
    }
}

// ---------------------------------------------------------------------------
// prep: diff + centered flow -> bufA channels 128..130 (NHWC fp16, stride 160)
// ---------------------------------------------------------------------------
__global__ void prep_kernel(const float* __restrict__ t1, const float* __restrict__ t2,
                            const float* __restrict__ flow, const float* __restrict__ means,
                            _Float16* __restrict__ bufA, size_t aSlot) {
    int n = blockIdx.x * 256 + threadIdx.x;
    if (n >= NPAD) return;
    int z = blockIdx.y;
    _Float16* dst = bufA + (size_t)z * aSlot + (size_t)n * 160 + 128;
    int y = n / PW2, x = n - PW2 * y;
    if (y < 1 || y > HH || x < 1 || x > WW) {
        dst[0] = (_Float16)0.f; dst[1] = (_Float16)0.f; dst[2] = (_Float16)0.f;
        return;
    }
    int iy = y - 1, ix = x - 1, pix = iy * WW + ix;
    const float* fb = flow + (size_t)z * 2 * HW;
    float fx = fb[pix];
    float fy = fb[HW + pix];
    float sx = (float)ix + fx * 5.0f;
    float sy = (float)iy + fy * 5.0f;
    float fx0 = floorf(sx), fy0 = floorf(sy);
    float wx1 = sx - fx0, wy1 = sy - fy0;
    float wx0 = 1.f - wx1, wy0 = 1.f - wy1;
    int ix0 = (int)fx0, iy0 = (int)fy0;
    bool y0ok = (iy0 >= 0) && (iy0 < HH);
    bool y1ok = (iy0 + 1 >= 0) && (iy0 + 1 < HH);
    bool x0ok = (ix0 >= 0) && (ix0 < WW);
    bool x1ok = (ix0 + 1 >= 0) && (ix0 + 1 < WW);
    float d2 = 0.f;
    for (int c = 0; c < 3; ++c) {
        const float* img = t2 + ((size_t)z * 3 + c) * HW;
        float v00 = (y0ok && x0ok) ? img[iy0 * WW + ix0] : 0.f;
        float v01 = (y0ok && x1ok) ? img[iy0 * WW + ix0 + 1] : 0.f;
        float v10 = (y1ok && x0ok) ? img[(iy0 + 1) * WW + ix0] : 0.f;
        float v11 = (y1ok && x1ok) ? img[(iy0 + 1) * WW + ix0 + 1] : 0.f;
        float v = v00 * (wy0 * wx0) + v01 * (wy0 * wx1) + v10 * (wy1 * wx0) + v11 * (wy1 * wx1);
        float d = t1[((size_t)z * 3 + c) * HW + pix] - v;
        d2 += d * d;
    }
    dst[0] = (_Float16)sqrtf(d2);
    dst[1] = (_Float16)(fx - means[z * 2 + 0]);
    dst[2] = (_Float16)(fy - means[z * 2 + 1]);
}

// ---------------------------------------------------------------------------
// fp16 MFMA implicit-GEMM conv.
//  - A (weights): direct global loads, contiguous 1KB fragments, L1/L2-hot.
//  - B (activations): async global_load_lds (width 16) into [pix][32] LDS
//    (stride-32: DMA dest = lane*16 exactly; b128 reads at 8-phase floor).
//  - 2 barriers per 32-K chunk (m97 pattern); 4 blocks/CU hide drains.
// ---------------------------------------------------------------------------
template <int BM, int KH, int KW, int CSIN, int NCHUNK, int CSOUT>
__launch_bounds__(256, 4)
__global__ void mfma_conv(const _Float16* __restrict__ in, size_t inSlot,
                          const _Float16* __restrict__ wt,
                          const float* __restrict__ bias,
                          _Float16* __restrict__ out, size_t outSlot) {
    constexpr int MT = BM / 32;  // 16-row m-tiles per wave (2x2 wave grid)
    __shared__ __align__(16) _Float16 Blds[128 * 32];
    const int t = threadIdx.x;
    const int wave = t >> 6, lane = t & 63;
    const int wm = wave >> 1, wn = wave & 1;
    const int col = lane & 15, quad = lane >> 4;
    const int n0 = blockIdx.x * 128;
    const _Float16* inImg = in + (size_t)blockIdx.z * inSlot;
    _Float16* outImg = out + (size_t)blockIdx.z * outSlot;

    // per-thread DMA source base: pixel = n0 + wave*16 + lane/4, slot = lane%4
    const _Float16* dmaBase =
        inImg + (ptrdiff_t)(n0 + wave * 16 + (lane >> 2)) * CSIN + (lane & 3) * 8;
    // wave-uniform LDS dest (lane*16B is implicit in global_load_lds)
    _Float16* dst0 = &Blds[(wave * 16) * 32];
    _Float16* dst1 = &Blds[(64 + wave * 16) * 32];
    // A fragment base: rows wm*MT*16+col, k-slice quad*8 (contiguous 1KB/frag)
    const _Float16* aBase = wt + ((size_t)(wm * MT * 16 + col)) * 32 + quad * 8;

    float4v acc[MT][4];
#pragma unroll
    for (int i = 0; i < MT; ++i)
#pragma unroll
        for (int j = 0; j < 4; ++j) acc[i][j] = float4v{0.f, 0.f, 0.f, 0.f};

#pragma unroll
    for (int s = 0; s < KH * KW; ++s) {
        const int off = (s / KW - KH / 2) * PW2 + (s % KW - KW / 2);
        const _Float16* gs = dmaBase + (ptrdiff_t)off * CSIN;
        const _Float16* as = aBase + (size_t)s * NCHUNK * BM * 32;
#pragma unroll
        for (int q = 0; q < NCHUNK; ++q) {
            __syncthreads();  // prior ds_reads complete before overwrite
            __builtin_amdgcn_global_load_lds(
                (const __attribute__((address_space(1))) void*)(gs + q * 32),
                (__attribute__((address_space(3))) void*)dst0, 16, 0, 0);
            __builtin_amdgcn_global_load_lds(
                (const __attribute__((address_space(1))) void*)(gs + q * 32 + 64 * CSIN),
                (__attribute__((address_space(3))) void*)dst1, 16, 0, 0);
            half8 aF[MT];
#pragma unroll
            for (int mt = 0; mt < MT; ++mt)
                aF[mt] = *(const half8*)(as + (size_t)q * BM * 32 + mt * 16 * 32);
            __syncthreads();  // vmcnt(0): DMA + A loads complete
            half8 bF[4];
#pragma unroll
            for (int nt = 0; nt < 4; ++nt)
                bF[nt] = *(const half8*)&Blds[(wn * 64 + nt * 16 + col) * 32 + quad * 8];
#pragma unroll
            for (int mt = 0; mt < MT; ++mt)
#pragma unroll
                for (int nt = 0; nt < 4; ++nt)
                    acc[mt][nt] = __builtin_amdgcn_mfma_f32_16x16x32_f16(
                        aF[mt], bF[nt], acc[mt][nt], 0, 0, 0);
        }
    }
    // epilogue: bias + lrelu + border mask, NHWC fp16 8B stores
#pragma unroll
    for (int mt = 0; mt < MT; ++mt) {
        const int m0 = wm * MT * 16 + mt * 16 + quad * 4;
        float bv[4];
#pragma unroll
        for (int i = 0; i < 4; ++i) bv[i] = bias[m0 + i];
#pragma unroll
        for (int nt = 0; nt < 4; ++nt) {
            int n = n0 + wn * 64 + nt * 16 + col;
            int y = n / PW2, x = n - y * PW2;
            bool ok = (y >= 1) && (y <= HH) && (x >= 1) && (x <= WW) && (n < NPAD);
            half4v h;
#pragma unroll
            for (int i = 0; i < 4; ++i) {
                float v = acc[mt][nt][i] + bv[i];
                v = (v >= 0.f) ? v : 0.1f * v;
                h[i] = ok ? (_Float16)v : (_Float16)0.f;
            }
            *(half4v*)&outImg[(size_t)n * CSOUT + m0] = h;
        }
    }
}

// ---------------------------------------------------------------------------
// dist1: 5x1 conv (pad 2,0), 32ch fp16 NHWC-padded in -> 25ch fp32 NHWC out
// ---------------------------------------------------------------------------
__global__ void dist1_kernel(const _Float16* __restrict__ in, size_t inSlot,
                             const float* __restrict__ w, const float* __restrict__ bias,
                             float* __restrict__ outD, size_t outSlot) {
    __shared__ float wl[25 * 32 * 5];
    int t = threadIdx.x;
    for (int i = t; i < 4000; i += 256) wl[i] = w[i];
    __syncthreads();
    int p = blockIdx.x * 256 + t;
    int z = blockIdx.y;
    const _Float16* inI = in + (size_t)z * inSlot;
    float* out = outD + (size_t)z * outSlot;
    int y = p / WW, x = p - y * WW;
    float acc[25];
#pragma unroll
    for (int oc = 0; oc < 25; ++oc) acc[oc] = bias[oc];
    for (int kh = 0; kh < 5; ++kh) {
        int yy = y + kh - 2;
        if (yy < 0 || yy >= HH) continue;
        const _Float16* src = inI + (size_t)((yy + 1) * PW2 + x + 1) * 32;
        _Float16 vals[32];
#pragma unroll
        for (int g = 0; g < 4; ++g) *(half8*)&vals[g * 8] = *(const half8*)&src[g * 8];
#pragma unroll
        for (int ic = 0; ic < 32; ++ic) {
            float v = (float)vals[ic];
#pragma unroll
            for (int oc = 0; oc < 25; ++oc)
                acc[oc] = fmaf(v, wl[(oc * 32 + ic) * 5 + kh], acc[oc]);
        }
    }
#pragma unroll
    for (int oc = 0; oc < 25; ++oc) out[(size_t)p * 25 + oc] = acc[oc];
}

// ---------------------------------------------------------------------------
// final fused: dist2 (1x5) + softmax(-(d^2)) + unfold-weighted flow average
// ---------------------------------------------------------------------------
__global__ void final_kernel(const float* __restrict__ D1, size_t d1Slot,
                             const float* __restrict__ flow,
                             const float* __restrict__ dw2, const float* __restrict__ db2,
                             const float* __restrict__ sxw, const float* __restrict__ sxb,
                             const float* __restrict__ syw, const float* __restrict__ syb,
                             float* __restrict__ out) {
    __shared__ float wl[25 * 25 * 5];
    int t = threadIdx.x;
    for (int i = t; i < 3125; i += 256) wl[i] = dw2[i];
    __syncthreads();
    int p = blockIdx.x * 256 + t;
    int z = blockIdx.y;
    const float* D = D1 + (size_t)z * d1Slot;
    int y = p / WW, x = p - y * WW;
    float acc[25];
#pragma unroll
    for (int oc = 0; oc < 25; ++oc) acc[oc] = db2[oc];
    for (int kw = 0; kw < 5; ++kw) {
        int xx = x + kw - 2;
        if (xx < 0 || xx >= WW) continue;
        const float* src = D + (size_t)(y * WW + xx) * 25;
#pragma unroll
        for (int ic = 0; ic < 25; ++ic) {
            float v = src[ic];
#pragma unroll
            for (int oc = 0; oc < 25; ++oc)
                acc[oc] = fmaf(v, wl[(oc * 25 + ic) * 5 + kw], acc[oc]);
        }
    }
    float e[25];
    float m = -1e30f;
#pragma unroll
    for (int c = 0; c < 25; ++c) {
        float d = -(acc[c] * acc[c]);
        e[c] = d;
        m = fmaxf(m, d);
    }
    float s = 0.f;
#pragma unroll
    for (int c = 0; c < 25; ++c) {
        e[c] = expf(e[c] - m);
        s += e[c];
    }
    const float* f0 = flow + (size_t)z * 2 * HW;
    const float* f1 = f0 + HW;
    float ax = sxb[0], ay = syb[0];
#pragma unroll
    for (int kh = 0; kh < 5; ++kh) {
        int iy = y + kh - 2;
        bool yok = (iy >= 0) && (iy < HH);
#pragma unroll
        for (int kw = 0; kw < 5; ++kw) {
            int ix = x + kw - 2;
            int c = kh * 5 + kw;
            float u1 = 0.f, u2 = 0.f;
            if (yok && ix >= 0 && ix < WW) {
                int q = iy * WW + ix;
                u1 = f0[q];
                u2 = f1[q];
            }
            ax = fmaf(e[c] * u1, sxw[c], ax);
            ay = fmaf(e[c] * u2, syw[c], ay);
        }
    }
    float inv = 1.0f / s;
    out[(size_t)z * 2 * HW + p] = ax * inv;
    out[(size_t)z * 2 * HW + HW + p] = ay * inv;
}

// ---------------------------------------------------------------------------
extern "C" void kernel_launch(void* const* d_in, const int* in_sizes, int n_in,
                              void* d_out, int out_size, void* d_ws, size_t ws_size,
                              hipStream_t stream) {
    const float* t1      = (const float*)d_in[0];
    const float* t2      = (const float*)d_in[1];
    const float* feat_in = (const float*)d_in[2];
    const float* flow    = (const float*)d_in[4];
    const float* feat_w  = (const float*)d_in[5];
    const float* feat_b  = (const float*)d_in[6];
    const float* w1 = (const float*)d_in[7];   const float* b1 = (const float*)d_in[8];
    const float* w2 = (const float*)d_in[9];   const float* b2 = (const float*)d_in[10];
    const float* w3 = (const float*)d_in[11];  const float* b3 = (const float*)d_in[12];
    const float* w4 = (const float*)d_in[13];  const float* b4 = (const float*)d_in[14];
    const float* w5 = (const float*)d_in[15];  const float* b5 = (const float*)d_in[16];
    const float* w6 = (const float*)d_in[17];  const float* b6 = (const float*)d_in[18];
    const float* dw1 = (const float*)d_in[19]; const float* db1 = (const float*)d_in[20];
    const float* dw2 = (const float*)d_in[21]; const float* db2 = (const float*)d_in[22];
    const float* sxw = (const float*)d_in[23]; const float* sxb = (const float*)d_in[24];
    const float* syw = (const float*)d_in[25]; const float* syb = (const float*)d_in[26];
    float* out = (float*)d_out;
    char* ws = (char*)d_ws;

    // Wt layout offsets (fp16 elems)
    const size_t OFF_FEAT = 0;        // 1 shift x 2 chunks x 128 x 32 = 8192
    const size_t OFF_C1 = 8192;       // 9x5x128x32 = 184320
    const size_t OFF_C2 = 192512;     // 9x4x128x32 = 147456
    const size_t OFF_C3 = 339968;     // 9x4x64x32  = 73728
    const size_t OFF_C4 = 413696;     // 9x2x64x32  = 36864
    const size_t OFF_C5 = 450560;     // 9x2x32x32  = 18432
    const size_t OFF_C6 = 468992;     // 9x1x32x32  = 9216
    const size_t WT_BYTES = 478208 * 2;  // 956416

    _Float16* wt = (_Float16*)ws;
    float* means = (float*)(ws + WT_BYTES);           // 32 B
    const size_t F0 = WT_BYTES + 64;                  // 956480, 16B aligned
    const size_t F_SLOT_B = (size_t)(NPADT + 2 * GUARD) * 64 * 2;   // 11,468,800
    const size_t A_SLOT_B = (size_t)(NPADT + 2 * GUARD) * 160 * 2;  // 28,672,000
    const size_t B_SLOT_B = (size_t)(NPADT + 2 * GUARD) * 128 * 2;  // 22,937,600
    const size_t C_SLOT_B = B_SLOT_B;
    const size_t PER_IMG = F_SLOT_B + A_SLOT_B + B_SLOT_B + C_SLOT_B;  // 86,016,000
    const size_t needFull = F0 + NB * PER_IMG;
    const int step = (ws_size >= needFull) ? NB : 1;

    const size_t A0 = F0 + step * F_SLOT_B;
    const size_t B0 = A0 + step * A_SLOT_B;
    const size_t C0 = B0 + step * B_SLOT_B;

    // data bases (past guard) per channel-stride interpretation
    _Float16* Fd    = (_Float16*)(ws + F0) + (size_t)GUARD * 64;
    _Float16* Ad    = (_Float16*)(ws + A0) + (size_t)GUARD * 160;
    _Float16* Bd128 = (_Float16*)(ws + B0) + (size_t)GUARD * 128;
    _Float16* Bd64  = (_Float16*)(ws + B0) + (size_t)GUARD * 64;
    _Float16* Bd32  = (_Float16*)(ws + B0) + (size_t)GUARD * 32;
    _Float16* Cd128 = (_Float16*)(ws + C0) + (size_t)GUARD * 128;
    _Float16* Cd64  = (_Float16*)(ws + C0) + (size_t)GUARD * 64;
    _Float16* Cd32  = (_Float16*)(ws + C0) + (size_t)GUARD * 32;
    float* D1 = (float*)(ws + F0);  // reuses F region (dead after feat conv)

    const size_t FSL = F_SLOT_B / 2, ASL = A_SLOT_B / 2, BSL = B_SLOT_B / 2,
                 CSL = C_SLOT_B / 2, DSL = F_SLOT_B / 4;

    mean_kernel<<<8, 256, 0, stream>>>(flow, means);

    // weight transforms (run every call; ws is re-poisoned)
    auto wlaunch = [&](const float* src, size_t dst, int cin, int nch, int cout,
                       int nsh, int perm) {
        int total = nsh * nch * cout * 32;
        wtrans_kernel<<<(total + 255) / 256, 256, 0, stream>>>(
            src, wt + dst, cin, nch, cout, nsh, perm, total);
    };
    wlaunch(feat_w, OFF_FEAT, 64, 2, 128, 1, 0);
    wlaunch(w1, OFF_C1, 131, 5, 128, 9, 1);
    wlaunch(w2, OFF_C2, 128, 4, 128, 9, 0);
    wlaunch(w3, OFF_C3, 128, 4, 64, 9, 0);
    wlaunch(w4, OFF_C4, 64, 2, 64, 9, 0);
    wlaunch(w5, OFF_C5, 64, 2, 32, 9, 0);
    wlaunch(w6, OFF_C6, 32, 1, 32, 9, 0);

    const int NT = NPADT / 128;  // 684 N-tiles per image

    for (int b0 = 0; b0 < NB; b0 += step) {
        dim3 gconv(NT, 1, step);
        feat_transpose<<<dim3(HW / 64, step), 256, 0, stream>>>(
            feat_in + (size_t)b0 * 64 * HW, Fd, FSL);
        prep_kernel<<<dim3((NPAD + 255) / 256, step), 256, 0, stream>>>(
            t1 + (size_t)b0 * 3 * HW, t2 + (size_t)b0 * 3 * HW,
            flow + (size_t)b0 * 2 * HW, means + b0 * 2, Ad, ASL);
        mfma_conv<128, 1, 1, 64, 2, 160><<<gconv, 256, 0, stream>>>(
            Fd, FSL, wt + OFF_FEAT, feat_b, Ad, ASL);
        mfma_conv<128, 3, 3, 160, 5, 128><<<gconv, 256, 0, stream>>>(
            Ad, ASL, wt + OFF_C1, b1, Bd128, BSL);
        mfma_conv<128, 3, 3, 128, 4, 128><<<gconv, 256, 0, stream>>>(
            Bd128, BSL, wt + OFF_C2, b2, Cd128, CSL);
        mfma_conv<64, 3, 3, 128, 4, 64><<<gconv, 256, 0, stream>>>(
            Cd128, CSL, wt + OFF_C3, b3, Bd64, BSL);
        mfma_conv<64, 3, 3, 64, 2, 64><<<gconv, 256, 0, stream>>>(
            Bd64, BSL, wt + OFF_C4, b4, Cd64, CSL);
        mfma_conv<32, 3, 3, 64, 2, 32><<<gconv, 256, 0, stream>>>(
            Cd64, CSL, wt + OFF_C5, b5, Bd32, BSL);
        mfma_conv<32, 3, 3, 32, 1, 32><<<gconv, 256, 0, stream>>>(
            Bd32, BSL, wt + OFF_C6, b6, Cd32, CSL);
        dist1_kernel<<<dim3(HW / 256, step), 256, 0, stream>>>(
            Cd32, CSL, dw1, db1, D1, DSL);
        final_kernel<<<dim3(HW / 256, step), 256, 0, stream>>>(
            D1, DSL, flow + (size_t)b0 * 2 * HW, dw2, db2, sxw, sxb, syw, syb,
            out + (size_t)b0 * 2 * HW);
    }
}

// Round 5
// 1106.187 us; speedup vs baseline: 1.4779x; 1.1285x over previous
//
#include <hip/hip_runtime.h>
#include <math.h>

#define HH 192
#define WW 448
#define HW (HH * WW)      // 86016
#define PW2 450           // padded width
#define PH2 194           // padded height
#define NPAD 87300        // 194*450 valid padded pixels
#define NPADT 87552       // padded to 684*128 tiles
#define GUARD 1024        // guard pixels before/after each buffer
#define NB 4

typedef _Float16 half8 __attribute__((ext_vector_type(8)));
typedef _Float16 half4v __attribute__((ext_vector_type(4)));
typedef float float4v __attribute__((ext_vector_type(4)));

// ---------------------------------------------------------------------------
// per-(b,c) mean of flow over H*W  -> means[8]
// ---------------------------------------------------------------------------
__global__ void mean_kernel(const float* __restrict__ flow, float* __restrict__ means) {
    int bc = blockIdx.x;
    const float* src = flow + (size_t)bc * HW;
    float s = 0.f;
    for (int i = threadIdx.x; i < HW; i += 256) s += src[i];
    __shared__ float red[256];
    red[threadIdx.x] = s;
    __syncthreads();
    for (int off = 128; off > 0; off >>= 1) {
        if (threadIdx.x < off) red[threadIdx.x] += red[threadIdx.x + off];
        __syncthreads();
    }
    if (threadIdx.x == 0) means[bc] = red[0] * (1.0f / (float)HW);
}

// ---------------------------------------------------------------------------
// weight transform: OIHW fp32 -> [shift][chunk][oc][k=32] fp16, zero-padded K
// perm=1: conv1 channel permutation (buffer: 0..127=feat->ref ic 3..130,
//         128..130 = diff,fx,fy -> ref ic 0..2, 131..159 -> zero)
// ---------------------------------------------------------------------------
__global__ void wtrans_kernel(const float* __restrict__ w, _Float16* __restrict__ wt,
                              int cinReal, int nchunk, int cout, int nshift, int perm,
                              int total) {
    int idx = blockIdx.x * 256 + threadIdx.x;
    if (idx >= total) return;
    int k = idx & 31;
    int r = idx >> 5;
    int m = r % cout;
    int r2 = r / cout;
    int q = r2 % nchunk;
    int s = r2 / nchunk;
    int icb = q * 32 + k;
    float val = 0.f;
    if (perm) {
        if (icb < 131) {
            int icr = (icb < 128) ? icb + 3 : icb - 128;
            val = w[((size_t)m * cinReal + icr) * nshift + s];
        }
    } else if (icb < cinReal) {
        val = w[((size_t)m * cinReal + icb) * nshift + s];
    }
    wt[idx] = (_Float16)val;
}

// ---------------------------------------------------------------------------
// features NCHW fp32 -> padded NHWC fp16 (64 ch), LDS-tiled transpose
// ---------------------------------------------------------------------------
__global__ void feat_transpose(const float* __restrict__ feat, _Float16* __restrict__ F,
                               size_t fSlot) {
    __shared__ _Float16 tile[64 * 72];
    int t = threadIdx.x;
    int z = blockIdx.y;
    int pix0 = blockIdx.x * 64;  // 64 | 448 -> never crosses a row
    const float* src = feat + (size_t)z * 64 * HW + pix0;
#pragma unroll
    for (int pass = 0; pass < 16; ++pass) {
        int c = pass * 4 + (t >> 6);
        int pl = t & 63;
        tile[pl * 72 + c] = (_Float16)src[(size_t)c * HW + pl];
    }
    __syncthreads();
    int row = pix0 / WW;
    int xcol = pix0 - row * WW;
    size_t n0 = (size_t)(row + 1) * PW2 + xcol + 1;
    _Float16* dst = F + (size_t)z * fSlot + n0 * 64;
#pragma unroll
    for (int pass = 0; pass < 2; ++pass) {
        int pl = (t >> 3) + pass * 32;
        int seg = t & 7;
        *(half8*)&dst[(size_t)pl * 64 + seg * 8] = *(const half8*)&tile[pl * 72 + seg * 8];
    }
}

// ---------------------------------------------------------------------------
// prep: diff + centered flow -> bufA channels 128..130 (NHWC fp16, stride 160)
// ---------------------------------------------------------------------------
__global__ void prep_kernel(const float* __restrict__ t1, const float* __restrict__ t2,
                            const float* __restrict__ flow, const float* __restrict__ means,
                            _Float16* __restrict__ bufA, size_t aSlot) {
    int n = blockIdx.x * 256 + threadIdx.x;
    if (n >= NPAD) return;
    int z = blockIdx.y;
    _Float16* dst = bufA + (size_t)z * aSlot + (size_t)n * 160 + 128;
    int y = n / PW2, x = n - PW2 * y;
    if (y < 1 || y > HH || x < 1 || x > WW) {
        dst[0] = (_Float16)0.f; dst[1] = (_Float16)0.f; dst[2] = (_Float16)0.f;
        return;
    }
    int iy = y - 1, ix = x - 1, pix = iy * WW + ix;
    const float* fb = flow + (size_t)z * 2 * HW;
    float fx = fb[pix];
    float fy = fb[HW + pix];
    float sx = (float)ix + fx * 5.0f;
    float sy = (float)iy + fy * 5.0f;
    float fx0 = floorf(sx), fy0 = floorf(sy);
    float wx1 = sx - fx0, wy1 = sy - fy0;
    float wx0 = 1.f - wx1, wy0 = 1.f - wy1;
    int ix0 = (int)fx0, iy0 = (int)fy0;
    bool y0ok = (iy0 >= 0) && (iy0 < HH);
    bool y1ok = (iy0 + 1 >= 0) && (iy0 + 1 < HH);
    bool x0ok = (ix0 >= 0) && (ix0 < WW);
    bool x1ok = (ix0 + 1 >= 0) && (ix0 + 1 < WW);
    float d2 = 0.f;
    for (int c = 0; c < 3; ++c) {
        const float* img = t2 + ((size_t)z * 3 + c) * HW;
        float v00 = (y0ok && x0ok) ? img[iy0 * WW + ix0] : 0.f;
        float v01 = (y0ok && x1ok) ? img[iy0 * WW + ix0 + 1] : 0.f;
        float v10 = (y1ok && x0ok) ? img[(iy0 + 1) * WW + ix0] : 0.f;
        float v11 = (y1ok && x1ok) ? img[(iy0 + 1) * WW + ix0 + 1] : 0.f;
        float v = v00 * (wy0 * wx0) + v01 * (wy0 * wx1) + v10 * (wy1 * wx0) + v11 * (wy1 * wx1);
        float d = t1[((size_t)z * 3 + c) * HW + pix] - v;
        d2 += d * d;
    }
    dst[0] = (_Float16)sqrtf(d2);
    dst[1] = (_Float16)(fx - means[z * 2 + 0]);
    dst[2] = (_Float16)(fy - means[z * 2 + 1]);
}

// ---------------------------------------------------------------------------
// fp16 MFMA implicit-GEMM conv, row-staged K-loop.
//  - Per dy (3 stages for 3x3): DMA the contiguous (BN+2)*CSIN strip into LDS
//    once (global_load_lds w16); all 3 dx shifts + all K-chunks read from it.
//    -> 2 barriers per stage (6 total) with 100-240 MFMAs between pairs.
//  - A (weights): direct global b128 loads, L2-hot, scheduled freely.
//  - XCD band swizzle: blocks with equal id%8 cover a contiguous strip band
//    (~1/8 image fits per-XCD 4MB L2) -> vertical/dy re-reads become L2 hits.
//  - Wave grid: WM x WN (2x2 for BM>=64, 1x4 for BM=32 with BN=256).
// ---------------------------------------------------------------------------
template <int BM, int WN, int K3, int CSIN, int NCHUNK, int CSOUT>
__launch_bounds__(256, 4)
__global__ void mfma_conv(const _Float16* __restrict__ in, size_t inSlot,
                          const _Float16* __restrict__ wt,
                          const float* __restrict__ bias,
                          _Float16* __restrict__ out, size_t outSlot, int NT) {
    constexpr int WM = 4 / WN;
    constexpr int MT = BM / (16 * WM);
    constexpr int BN = WN * 64;
    constexpr int HALO = K3 ? 2 : 0;
    constexpr int NSTG = K3 ? 3 : 1;   // dy stages
    constexpr int NSH = K3 ? 3 : 1;    // dx shifts per stage
    constexpr int NISSUE = (( (BN + HALO) * CSIN * 2) + 4095) / 4096;
    __shared__ __align__(16) _Float16 Blds[NISSUE * 2048];

    const int t = threadIdx.x;
    const int wave = t >> 6, lane = t & 63;
    const int wm = wave / WN, wn = wave % WN;
    const int col = lane & 15, quad = lane >> 4;

    // XCD band swizzle (gridDim.x is a multiple of 8; tail blocks idle)
    const int band = (int)(gridDim.x >> 3);
    const int sblk = (blockIdx.x & 7) * band + (blockIdx.x >> 3);
    if (sblk >= NT) return;
    const int n0 = sblk * BN;

    const _Float16* inImg = in + (size_t)blockIdx.z * inSlot;
    _Float16* outImg = out + (size_t)blockIdx.z * outSlot;

    // per-lane A fragment base (pre-swizzled weights, contiguous 16B/lane)
    const _Float16* aBase = wt + ((size_t)(wm * MT * 16 + col)) * 32 + quad * 8;
    // strip origin (n0-1 for 3x3 halo)
    const _Float16* strip0 = inImg + (ptrdiff_t)(n0 - (K3 ? 1 : 0)) * CSIN;
    const int local = wn * 64 + col;  // pixel within block tile (per nt: +nt*16)

    float4v acc[MT][4];
#pragma unroll
    for (int i = 0; i < MT; ++i)
#pragma unroll
        for (int j = 0; j < 4; ++j) acc[i][j] = float4v{0.f, 0.f, 0.f, 0.f};

#pragma unroll
    for (int stg = 0; stg < NSTG; ++stg) {
        const _Float16* src = strip0 + (ptrdiff_t)(stg - (K3 ? 1 : 0)) * PW2 * CSIN;
        __syncthreads();  // all waves done reading previous stage's LDS
#pragma unroll
        for (int j = 0; j < NISSUE; ++j)
            __builtin_amdgcn_global_load_lds(
                (const __attribute__((address_space(1))) void*)(src + (j * 256 + t) * 8),
                (__attribute__((address_space(3))) void*)&Blds[(j * 256 + wave * 64) * 8],
                16, 0, 0);
        __syncthreads();  // vmcnt drain: strip visible
#pragma unroll
        for (int dx = 0; dx < NSH; ++dx) {
            const int s = K3 ? (stg * 3 + dx) : 0;
            const _Float16* as = aBase + (size_t)s * NCHUNK * BM * 32;
#pragma unroll
            for (int q = 0; q < NCHUNK; ++q) {
                half8 aF[MT];
#pragma unroll
                for (int mt = 0; mt < MT; ++mt)
                    aF[mt] = *(const half8*)(as + (size_t)q * BM * 32 + mt * 512);
                half8 bF[4];
#pragma unroll
                for (int nt = 0; nt < 4; ++nt)
                    bF[nt] = *(const half8*)&Blds[((K3 ? dx : 0) + local + nt * 16) * CSIN +
                                                  q * 32 + quad * 8];
#pragma unroll
                for (int mt = 0; mt < MT; ++mt)
#pragma unroll
                    for (int nt = 0; nt < 4; ++nt)
                        acc[mt][nt] = __builtin_amdgcn_mfma_f32_16x16x32_f16(
                            aF[mt], bF[nt], acc[mt][nt], 0, 0, 0);
            }
        }
    }
    // epilogue: bias + lrelu + border mask, NHWC fp16 8B stores
#pragma unroll
    for (int mt = 0; mt < MT; ++mt) {
        const int m0 = wm * MT * 16 + mt * 16 + quad * 4;
        float bv[4];
#pragma unroll
        for (int i = 0; i < 4; ++i) bv[i] = bias[m0 + i];
#pragma unroll
        for (int nt = 0; nt < 4; ++nt) {
            int n = n0 + wn * 64 + nt * 16 + col;
            int y = n / PW2, x = n - y * PW2;
            bool ok = (y >= 1) && (y <= HH) && (x >= 1) && (x <= WW) && (n < NPAD);
            half4v h;
#pragma unroll
            for (int i = 0; i < 4; ++i) {
                float v = acc[mt][nt][i] + bv[i];
                v = (v >= 0.f) ? v : 0.1f * v;
                h[i] = ok ? (_Float16)v : (_Float16)0.f;
            }
            *(half4v*)&outImg[(size_t)n * CSOUT + m0] = h;
        }
    }
}

// ---------------------------------------------------------------------------
// dist1: 5x1 conv (pad 2,0), 32ch fp16 NHWC-padded in -> 25ch fp32 NHWC out
// ---------------------------------------------------------------------------
__global__ void dist1_kernel(const _Float16* __restrict__ in, size_t inSlot,
                             const float* __restrict__ w, const float* __restrict__ bias,
                             float* __restrict__ outD, size_t outSlot) {
    __shared__ float wl[25 * 32 * 5];
    int t = threadIdx.x;
    for (int i = t; i < 4000; i += 256) wl[i] = w[i];
    __syncthreads();
    int p = blockIdx.x * 256 + t;
    int z = blockIdx.y;
    const _Float16* inI = in + (size_t)z * inSlot;
    float* out = outD + (size_t)z * outSlot;
    int y = p / WW, x = p - y * WW;
    float acc[25];
#pragma unroll
    for (int oc = 0; oc < 25; ++oc) acc[oc] = bias[oc];
    for (int kh = 0; kh < 5; ++kh) {
        int yy = y + kh - 2;
        if (yy < 0 || yy >= HH) continue;
        const _Float16* src = inI + (size_t)((yy + 1) * PW2 + x + 1) * 32;
        _Float16 vals[32];
#pragma unroll
        for (int g = 0; g < 4; ++g) *(half8*)&vals[g * 8] = *(const half8*)&src[g * 8];
#pragma unroll
        for (int ic = 0; ic < 32; ++ic) {
            float v = (float)vals[ic];
#pragma unroll
            for (int oc = 0; oc < 25; ++oc)
                acc[oc] = fmaf(v, wl[(oc * 32 + ic) * 5 + kh], acc[oc]);
        }
    }
#pragma unroll
    for (int oc = 0; oc < 25; ++oc) out[(size_t)p * 25 + oc] = acc[oc];
}

// ---------------------------------------------------------------------------
// final fused: dist2 (1x5) + softmax(-(d^2)) + unfold-weighted flow average
// ---------------------------------------------------------------------------
__global__ void final_kernel(const float* __restrict__ D1, size_t d1Slot,
                             const float* __restrict__ flow,
                             const float* __restrict__ dw2, const float* __restrict__ db2,
                             const float* __restrict__ sxw, const float* __restrict__ sxb,
                             const float* __restrict__ syw, const float* __restrict__ syb,
                             float* __restrict__ out) {
    __shared__ float wl[25 * 25 * 5];
    int t = threadIdx.x;
    for (int i = t; i < 3125; i += 256) wl[i] = dw2[i];
    __syncthreads();
    int p = blockIdx.x * 256 + t;
    int z = blockIdx.y;
    const float* D = D1 + (size_t)z * d1Slot;
    int y = p / WW, x = p - y * WW;
    float acc[25];
#pragma unroll
    for (int oc = 0; oc < 25; ++oc) acc[oc] = db2[oc];
    for (int kw = 0; kw < 5; ++kw) {
        int xx = x + kw - 2;
        if (xx < 0 || xx >= WW) continue;
        const float* src = D + (size_t)(y * WW + xx) * 25;
#pragma unroll
        for (int ic = 0; ic < 25; ++ic) {
            float v = src[ic];
#pragma unroll
            for (int oc = 0; oc < 25; ++oc)
                acc[oc] = fmaf(v, wl[(oc * 25 + ic) * 5 + kw], acc[oc]);
        }
    }
    float e[25];
    float m = -1e30f;
#pragma unroll
    for (int c = 0; c < 25; ++c) {
        float d = -(acc[c] * acc[c]);
        e[c] = d;
        m = fmaxf(m, d);
    }
    float s = 0.f;
#pragma unroll
    for (int c = 0; c < 25; ++c) {
        e[c] = expf(e[c] - m);
        s += e[c];
    }
    const float* f0 = flow + (size_t)z * 2 * HW;
    const float* f1 = f0 + HW;
    float ax = sxb[0], ay = syb[0];
#pragma unroll
    for (int kh = 0; kh < 5; ++kh) {
        int iy = y + kh - 2;
        bool yok = (iy >= 0) && (iy < HH);
#pragma unroll
        for (int kw = 0; kw < 5; ++kw) {
            int ix = x + kw - 2;
            int c = kh * 5 + kw;
            float u1 = 0.f, u2 = 0.f;
            if (yok && ix >= 0 && ix < WW) {
                int q = iy * WW + ix;
                u1 = f0[q];
                u2 = f1[q];
            }
            ax = fmaf(e[c] * u1, sxw[c], ax);
            ay = fmaf(e[c] * u2, syw[c], ay);
        }
    }
    float inv = 1.0f / s;
    out[(size_t)z * 2 * HW + p] = ax * inv;
    out[(size_t)z * 2 * HW + HW + p] = ay * inv;
}

// ---------------------------------------------------------------------------
extern "C" void kernel_launch(void* const* d_in, const int* in_sizes, int n_in,
                              void* d_out, int out_size, void* d_ws, size_t ws_size,
                              hipStream_t stream) {
    const float* t1      = (const float*)d_in[0];
    const float* t2      = (const float*)d_in[1];
    const float* feat_in = (const float*)d_in[2];
    const float* flow    = (const float*)d_in[4];
    const float* feat_w  = (const float*)d_in[5];
    const float* feat_b  = (const float*)d_in[6];
    const float* w1 = (const float*)d_in[7];   const float* b1 = (const float*)d_in[8];
    const float* w2 = (const float*)d_in[9];   const float* b2 = (const float*)d_in[10];
    const float* w3 = (const float*)d_in[11];  const float* b3 = (const float*)d_in[12];
    const float* w4 = (const float*)d_in[13];  const float* b4 = (const float*)d_in[14];
    const float* w5 = (const float*)d_in[15];  const float* b5 = (const float*)d_in[16];
    const float* w6 = (const float*)d_in[17];  const float* b6 = (const float*)d_in[18];
    const float* dw1 = (const float*)d_in[19]; const float* db1 = (const float*)d_in[20];
    const float* dw2 = (const float*)d_in[21]; const float* db2 = (const float*)d_in[22];
    const float* sxw = (const float*)d_in[23]; const float* sxb = (const float*)d_in[24];
    const float* syw = (const float*)d_in[25]; const float* syb = (const float*)d_in[26];
    float* out = (float*)d_out;
    char* ws = (char*)d_ws;

    // Wt layout offsets (fp16 elems)
    const size_t OFF_FEAT = 0;        // 1 shift x 2 chunks x 128 x 32 = 8192
    const size_t OFF_C1 = 8192;       // 9x5x128x32 = 184320
    const size_t OFF_C2 = 192512;     // 9x4x128x32 = 147456
    const size_t OFF_C3 = 339968;     // 9x4x64x32  = 73728
    const size_t OFF_C4 = 413696;     // 9x2x64x32  = 36864
    const size_t OFF_C5 = 450560;     // 9x2x32x32  = 18432
    const size_t OFF_C6 = 468992;     // 9x1x32x32  = 9216
    const size_t WT_BYTES = 478208 * 2;  // 956416

    _Float16* wt = (_Float16*)ws;
    float* means = (float*)(ws + WT_BYTES);           // 32 B
    const size_t F0 = WT_BYTES + 64;                  // 956480, 16B aligned
    const size_t F_SLOT_B = (size_t)(NPADT + 2 * GUARD) * 64 * 2;   // 11,468,800
    const size_t A_SLOT_B = (size_t)(NPADT + 2 * GUARD) * 160 * 2;  // 28,672,000
    const size_t B_SLOT_B = (size_t)(NPADT + 2 * GUARD) * 128 * 2;  // 22,937,600
    const size_t C_SLOT_B = B_SLOT_B;
    const size_t PER_IMG = F_SLOT_B + A_SLOT_B + B_SLOT_B + C_SLOT_B;  // 86,016,000
    const size_t needFull = F0 + NB * PER_IMG;
    const int step = (ws_size >= needFull) ? NB : 1;

    const size_t A0 = F0 + step * F_SLOT_B;
    const size_t B0 = A0 + step * A_SLOT_B;
    const size_t C0 = B0 + step * B_SLOT_B;

    // data bases (past guard) per channel-stride interpretation
    _Float16* Fd    = (_Float16*)(ws + F0) + (size_t)GUARD * 64;
    _Float16* Ad    = (_Float16*)(ws + A0) + (size_t)GUARD * 160;
    _Float16* Bd128 = (_Float16*)(ws + B0) + (size_t)GUARD * 128;
    _Float16* Bd64  = (_Float16*)(ws + B0) + (size_t)GUARD * 64;
    _Float16* Bd32  = (_Float16*)(ws + B0) + (size_t)GUARD * 32;
    _Float16* Cd128 = (_Float16*)(ws + C0) + (size_t)GUARD * 128;
    _Float16* Cd64  = (_Float16*)(ws + C0) + (size_t)GUARD * 64;
    _Float16* Cd32  = (_Float16*)(ws + C0) + (size_t)GUARD * 32;
    float* D1 = (float*)(ws + F0);  // reuses F region (dead after feat conv)

    const size_t FSL = F_SLOT_B / 2, ASL = A_SLOT_B / 2, BSL = B_SLOT_B / 2,
                 CSL = C_SLOT_B / 2, DSL = F_SLOT_B / 4;

    mean_kernel<<<8, 256, 0, stream>>>(flow, means);

    // weight transforms (run every call; ws is re-poisoned)
    auto wlaunch = [&](const float* src, size_t dst, int cin, int nch, int cout,
                       int nsh, int perm) {
        int total = nsh * nch * cout * 32;
        wtrans_kernel<<<(total + 255) / 256, 256, 0, stream>>>(
            src, wt + dst, cin, nch, cout, nsh, perm, total);
    };
    wlaunch(feat_w, OFF_FEAT, 64, 2, 128, 1, 0);
    wlaunch(w1, OFF_C1, 131, 5, 128, 9, 1);
    wlaunch(w2, OFF_C2, 128, 4, 128, 9, 0);
    wlaunch(w3, OFF_C3, 128, 4, 64, 9, 0);
    wlaunch(w4, OFF_C4, 64, 2, 64, 9, 0);
    wlaunch(w5, OFF_C5, 64, 2, 32, 9, 0);
    wlaunch(w6, OFF_C6, 32, 1, 32, 9, 0);

    const int NT128 = NPADT / 128;   // 684 N-tiles (BN=128)
    const int NT256 = NPADT / 256;   // 342 N-tiles (BN=256)
    const int NTP128 = 688;          // padded to x8 for XCD swizzle
    const int NTP256 = 344;

    for (int b0 = 0; b0 < NB; b0 += step) {
        feat_transpose<<<dim3(HW / 64, step), 256, 0, stream>>>(
            feat_in + (size_t)b0 * 64 * HW, Fd, FSL);
        prep_kernel<<<dim3((NPAD + 255) / 256, step), 256, 0, stream>>>(
            t1 + (size_t)b0 * 3 * HW, t2 + (size_t)b0 * 3 * HW,
            flow + (size_t)b0 * 2 * HW, means + b0 * 2, Ad, ASL);
        mfma_conv<128, 2, 0, 64, 2, 160><<<dim3(NTP128, 1, step), 256, 0, stream>>>(
            Fd, FSL, wt + OFF_FEAT, feat_b, Ad, ASL, NT128);
        mfma_conv<128, 2, 1, 160, 5, 128><<<dim3(NTP128, 1, step), 256, 0, stream>>>(
            Ad, ASL, wt + OFF_C1, b1, Bd128, BSL, NT128);
        mfma_conv<128, 2, 1, 128, 4, 128><<<dim3(NTP128, 1, step), 256, 0, stream>>>(
            Bd128, BSL, wt + OFF_C2, b2, Cd128, CSL, NT128);
        mfma_conv<64, 2, 1, 128, 4, 64><<<dim3(NTP128, 1, step), 256, 0, stream>>>(
            Cd128, CSL, wt + OFF_C3, b3, Bd64, BSL, NT128);
        mfma_conv<64, 2, 1, 64, 2, 64><<<dim3(NTP128, 1, step), 256, 0, stream>>>(
            Bd64, BSL, wt + OFF_C4, b4, Cd64, CSL, NT128);
        mfma_conv<32, 4, 1, 64, 2, 32><<<dim3(NTP256, 1, step), 256, 0, stream>>>(
            Cd64, CSL, wt + OFF_C5, b5, Bd32, BSL, NT256);
        mfma_conv<32, 4, 1, 32, 1, 32><<<dim3(NTP256, 1, step), 256, 0, stream>>>(
            Bd32, BSL, wt + OFF_C6, b6, Cd32, CSL, NT256);
        dist1_kernel<<<dim3(HW / 256, step), 256, 0, stream>>>(
            Cd32, CSL, dw1, db1, D1, DSL);
        final_kernel<<<dim3(HW / 256, step), 256, 0, stream>>>(
            D1, DSL, flow + (size_t)b0 * 2 * HW, dw2, db2, sxw, sxb, syw, syb,
            out + (size_t)b0 * 2 * HW);
    }
}